// Round 7
// baseline (342.312 us; speedup 1.0000x reference)
//
#include <hip/hip_runtime.h>
#include <cstdint>
#include <cstddef>

#define NPTS 21824
#define NB   64
#define NCLS 20
#define MAXN 150
#define NCHUNK 11
#define CHSZ 2048
#define CAP  186          // candidate cap: 150 <= count <= 186 after select

typedef unsigned long long u64;
typedef unsigned int u32;

// Levels: L0 [0,16384) d=128 s=8 | L1 [16384,20480) d=64 s=16
//         L2 [20480,21504) d=32 s=32 | L3 [21504,21760) d=16 s=64
//         L4 [21760,21824) d=8 s=128   (all bases 8-aligned)

// ---------------------------------------------------------------------------
// Byte-radix select over register keys (8/thread, 256 threads).
// Returns largest T with count(key >= T) >= MAXN, early-stopping once
// count <= CAP. Per-wave histograms kill cross-wave atomic contention;
// bin selection = wave-0 shuffle suffix-scan + ballot (no serial scan).
// Keys are distinct (unique point index in low bits) -> terminates by pass 8
// with count = above+1 <= 150. ~3 barriers/pass, typically 2-3 passes.
// ---------------------------------------------------------------------------
__device__ __forceinline__ u64 radix_select(const u64 (&key)[8],
                                            u32 (*hist)[256], int* sres)
{
    const int tid = threadIdx.x;
    const int wv  = tid >> 6;
    u64 P = 0, T = 0;
    int r = MAXN, above = 0;
    for (int pass = 0; pass < 8; ++pass) {
        const int sh = 56 - 8 * pass;
        hist[0][tid] = 0; hist[1][tid] = 0; hist[2][tid] = 0; hist[3][tid] = 0;
        __syncthreads();
        #pragma unroll
        for (int i = 0; i < 8; ++i) {
            u64 k = key[i];
            if (pass == 0 || (k >> (sh + 8)) == P)
                atomicAdd(&hist[wv][(u32)(k >> sh) & 255u], 1u);
        }
        __syncthreads();
        if (tid < 64) {   // wave 0: lane covers bins 4*lane..4*lane+3
            int h0 = hist[0][4*tid+0] + hist[1][4*tid+0] + hist[2][4*tid+0] + hist[3][4*tid+0];
            int h1 = hist[0][4*tid+1] + hist[1][4*tid+1] + hist[2][4*tid+1] + hist[3][4*tid+1];
            int h2 = hist[0][4*tid+2] + hist[1][4*tid+2] + hist[2][4*tid+2] + hist[3][4*tid+2];
            int h3 = hist[0][4*tid+3] + hist[1][4*tid+3] + hist[2][4*tid+3] + hist[3][4*tid+3];
            int s  = h0 + h1 + h2 + h3;
            int S  = s;                      // suffix over lanes >= tid
            #pragma unroll
            for (int off = 1; off < 64; off <<= 1) {
                int v = __shfl_down(S, off);
                if (tid + off < 64) S += v;
            }
            u64 mask = __ballot(S >= r);     // S non-increasing in lane
            int L = 63 - __builtin_clzll(mask);
            if (tid == L) {
                int cum = S - s;             // keys in lanes > L
                int hh[4] = {h0, h1, h2, h3};
                int sel = 4*L, selcnt = 0, rn = r, an = cum;
                #pragma unroll
                for (int j = 3; j >= 0; --j) {
                    if (cum + hh[j] >= r) {
                        sel = 4*L + j; selcnt = hh[j]; rn = r - cum; an = cum;
                        break;
                    }
                    cum += hh[j];
                }
                sres[0] = sel; sres[1] = rn; sres[2] = an; sres[3] = selcnt;
            }
        }
        __syncthreads();
        P = (P << 8) | (u64)(u32)sres[0];
        r = sres[1];
        above += sres[2];
        int count = above + sres[3];
        if (count <= CAP) { T = P << sh; break; }
    }
    return T;
}

// ---------------------------------------------------------------------------
__global__ void k_zero(u32* __restrict__ c)
{
    c[threadIdx.x] = 0u;    // 64 per-batch fan-in counters
}

// ---------------------------------------------------------------------------
// Fused kernel, grid (NCHUNK, NB):
//   phase A (every block): scores for its 2048 points, chunk-local select,
//     publish <=186 candidates to global, fence, fan-in atomicAdd.
//   phase B (last block per batch): merge 11x186 -> exact sorted top-150,
//     id recompute, decode, reference-exact class-offset NMS, outputs.
// ---------------------------------------------------------------------------
__global__ __launch_bounds__(256) void k_fused(
    const float* __restrict__ c0, const float* __restrict__ c1,
    const float* __restrict__ c2, const float* __restrict__ c3,
    const float* __restrict__ c4,
    const float* __restrict__ r0, const float* __restrict__ r1,
    const float* __restrict__ r2, const float* __restrict__ r3,
    const float* __restrict__ r4,
    const float* __restrict__ t0, const float* __restrict__ t1,
    const float* __restrict__ t2, const float* __restrict__ t3,
    const float* __restrict__ t4,
    u64* __restrict__ cand, u32* __restrict__ done,
    float* __restrict__ out)
{
    __shared__ u32 hist[4][256];
    __shared__ int sres[4];
    __shared__ int cnt;
    __shared__ int lastflag;
    __shared__ u64 win[CAP];
    __shared__ u64 srt[MAXN];
    __shared__ float bx0[MAXN], bx1[MAXN], bx2[MAXN], bx3[MAXN];
    __shared__ float ox1[MAXN], oy1[MAXN], ox2[MAXN], oy2[MAXN], area[MAXN];
    __shared__ float sc[MAXN];
    __shared__ int   idv[MAXN];
    __shared__ u64 sup[MAXN][3];
    __shared__ u64 keepw[3];
    __shared__ float shcmax;
    __shared__ float wmax[4];

    const int tid   = threadIdx.x;
    const int chunk = blockIdx.x;
    const int b     = blockIdx.y;

    // ---- phase A: scores + chunk-local candidate select -------------------
    {
        const int pl = tid * 8;
        const int p0 = chunk * CHSZ + pl;
        u64 key[8];
        #pragma unroll
        for (int i = 0; i < 8; ++i) key[i] = 0;

        if (p0 < NPTS) {
            const float* cp; const float* tp; int base; size_t hw;
            if (p0 < 16384)      { cp = c0; tp = t0; base = 0;     hw = 16384; }
            else if (p0 < 20480) { cp = c1; tp = t1; base = 16384; hw = 4096;  }
            else if (p0 < 21504) { cp = c2; tp = t2; base = 20480; hw = 1024;  }
            else if (p0 < 21760) { cp = c3; tp = t3; base = 21504; hw = 256;   }
            else                 { cp = c4; tp = t4; base = 21760; hw = 64;    }
            int q = p0 - base;
            const float* cb = cp + (size_t)b * NCLS * hw + q;

            float4 m0 = *reinterpret_cast<const float4*>(cb);
            float4 m1 = *reinterpret_cast<const float4*>(cb + 4);
            for (int c = 1; c < NCLS; ++c) {
                float4 v0 = *reinterpret_cast<const float4*>(cb + (size_t)c * hw);
                float4 v1 = *reinterpret_cast<const float4*>(cb + (size_t)c * hw + 4);
                m0.x = fmaxf(m0.x, v0.x); m0.y = fmaxf(m0.y, v0.y);
                m0.z = fmaxf(m0.z, v0.z); m0.w = fmaxf(m0.w, v0.w);
                m1.x = fmaxf(m1.x, v1.x); m1.y = fmaxf(m1.y, v1.y);
                m1.z = fmaxf(m1.z, v1.z); m1.w = fmaxf(m1.w, v1.w);
            }
            const float* tb = tp + (size_t)b * hw + q;
            float4 q0 = *reinterpret_cast<const float4*>(tb);
            float4 q1 = *reinterpret_cast<const float4*>(tb + 4);

            float mm[8] = {m0.x, m0.y, m0.z, m0.w, m1.x, m1.y, m1.z, m1.w};
            float cc[8] = {q0.x, q0.y, q0.z, q0.w, q1.x, q1.y, q1.z, q1.w};
            #pragma unroll
            for (int i = 0; i < 8; ++i) {
                // bit-exact to max-of-sigmoids: expf monotone, 1/(1+u) antitone
                float best = 1.0f / (1.0f + expf(-mm[i]));
                float sct  = 1.0f / (1.0f + expf(-cc[i]));
                float s    = sqrtf(__fmul_rn(best, sct));
                key[i] = ((u64)__float_as_uint(s) << 32)
                       | (u32)(21823 - (p0 + i));
            }
        }

        u64 T = radix_select(key, hist, sres);

        if (tid == 0) cnt = 0;
        __syncthreads();
        u64* outp = cand + ((size_t)b * NCHUNK + chunk) * CAP;
        #pragma unroll
        for (int i = 0; i < 8; ++i) {
            if (key[i] >= T) {
                int pos = atomicAdd(&cnt, 1);
                if (pos < CAP) outp[pos] = key[i];
            }
        }
        __syncthreads();
        for (int i = cnt + tid; i < CAP; i += 256) outp[i] = 0;  // pad
    }

    // ---- fan-in: last block of this batch proceeds to phase B -------------
    __threadfence();                 // release candidate writes (device scope)
    __syncthreads();
    if (tid == 0) {
        u32 old = atomicAdd(&done[b], 1u);
        lastflag = (old == NCHUNK - 1);
    }
    __syncthreads();
    if (!lastflag) return;
    __threadfence();                 // acquire other blocks' candidates

    // ---- phase B: merge + exact top-150 + decode + NMS --------------------
    const int NC2 = NCHUNK * CAP;    // 2046
    u64 key[8];
    #pragma unroll
    for (int j = 0; j < 8; ++j) {
        int i = j * 256 + tid;
        key[j] = (i < NC2) ? cand[(size_t)b * NC2 + i] : 0ull;
    }

    u64 T = radix_select(key, hist, sres);

    if (tid == 0) cnt = 0;
    if (tid < MAXN) srt[tid] = 0ull;
    __syncthreads();
    #pragma unroll
    for (int j = 0; j < 8; ++j) {
        if (key[j] >= T) {
            int pos = atomicAdd(&cnt, 1);
            if (pos < CAP) win[pos] = key[j];
        }
    }
    __syncthreads();
    int C = min(cnt, CAP);
    if (tid < C) {                   // rank-sort: distinct keys -> permutation
        u64 mk = win[tid]; int r = 0;
        for (int j = 0; j < C; ++j) r += (win[j] > mk) ? 1 : 0;
        if (r < MAXN) srt[r] = mk;
    }
    __syncthreads();

    // decode + exact id recompute for the 150 winners
    if (tid < MAXN) {
        u64 kk = srt[tid];
        sc[tid] = __uint_as_float((u32)(kk >> 32));
        int p   = 21823 - (int)(kk & 0x7FFFu);

        const float* rp; const float* cp; int base, dim, lg, st;
        if (p < 16384)      { rp = r0; cp = c0; base = 0;     dim = 128; lg = 7; st = 8;   }
        else if (p < 20480) { rp = r1; cp = c1; base = 16384; dim = 64;  lg = 6; st = 16;  }
        else if (p < 21504) { rp = r2; cp = c2; base = 20480; dim = 32;  lg = 5; st = 32;  }
        else if (p < 21760) { rp = r3; cp = c3; base = 21504; dim = 16;  lg = 4; st = 64;  }
        else                { rp = r4; cp = c4; base = 21760; dim = 8;   lg = 3; st = 128; }

        int q = p - base;
        size_t hw = (size_t)dim * dim;

        // exact argmax over sigmoids, first max wins (reference semantics)
        const float* cb = cp + (size_t)b * NCLS * hw + q;
        float best = -1.0f; int bi = 0;
        for (int c = 0; c < NCLS; ++c) {
            float v  = cb[(size_t)c * hw];
            float sg = 1.0f / (1.0f + expf(-v));
            if (sg > best) { best = sg; bi = c; }
        }
        idv[tid] = bi + 1;

        int y = q >> lg;
        int x = q & (dim - 1);
        float s  = (float)st;
        float cx = (float)(x * st + (st >> 1));
        float cy = (float)(y * st + (st >> 1));
        const float* rg = rp + (size_t)b * 4 * hw + q;
        float a0 = rg[0], a1 = rg[hw], a2 = rg[2 * hw], a3 = rg[3 * hw];
        bx0[tid] = __fsub_rn(cx, __fmul_rn(a0, s));
        bx1[tid] = __fsub_rn(cy, __fmul_rn(a1, s));
        bx2[tid] = __fadd_rn(cx, __fmul_rn(a2, s));
        bx3[tid] = __fadd_rn(cy, __fmul_rn(a3, s));
    }
    __syncthreads();

    // coord_max over valid boxes — shuffle reduce, 4 wave maxes
    float m = -INFINITY;
    if (tid < MAXN && sc[tid] > 0.05f)
        m = fmaxf(fmaxf(bx0[tid], bx1[tid]), fmaxf(bx2[tid], bx3[tid]));
    #pragma unroll
    for (int off = 32; off >= 1; off >>= 1) m = fmaxf(m, __shfl_xor(m, off));
    if ((tid & 63) == 0) wmax[tid >> 6] = m;
    if (tid < 192) {                 // valid mask via ballot (waves 0..2)
        bool val = (tid < MAXN) && (sc[tid] > 0.05f);
        u64 mask = __ballot(val);
        if ((tid & 63) == 0) keepw[tid >> 6] = mask;
    }
    __syncthreads();
    if (tid == 0) {
        float mm = fmaxf(fmaxf(wmax[0], wmax[1]), fmaxf(wmax[2], wmax[3]));
        shcmax = isfinite(mm) ? mm : 0.0f;
    }
    __syncthreads();

    float cm1 = __fadd_rn(shcmax, 1.0f);
    if (tid < MAXN) {
        float off = __fmul_rn((float)idv[tid], cm1);
        float X1 = __fadd_rn(bx0[tid], off);
        float Y1 = __fadd_rn(bx1[tid], off);
        float X2 = __fadd_rn(bx2[tid], off);
        float Y2 = __fadd_rn(bx3[tid], off);
        ox1[tid] = X1; oy1[tid] = Y1; ox2[tid] = X2; oy2[tid] = Y2;
        area[tid] = __fmul_rn(__fadd_rn(__fsub_rn(X2, X1), 1.0f),
                              __fadd_rn(__fsub_rn(Y2, Y1), 1.0f));
    }
    __syncthreads();

    // suppression bitmask rows: 450 tasks over 256 threads
    for (int t = tid; t < MAXN * 3; t += 256) {
        int i = t / 3;
        int w = t - i * 3;
        float x1i = ox1[i], y1i = oy1[i], x2i = ox2[i], y2i = oy2[i], ai = area[i];
        u64 bits = 0ull;
        for (int e = 0; e < 64; ++e) {
            int j = w * 64 + e;
            if (j >= MAXN) break;
            float xmin = fmaxf(x1i, ox1[j]);
            float ymin = fmaxf(y1i, oy1[j]);
            float xmax = fminf(x2i, ox2[j]);
            float ymax = fminf(y2i, oy2[j]);
            float ow = fmaxf(__fsub_rn(xmax, xmin), 0.0f);
            float oh = fmaxf(__fsub_rn(ymax, ymin), 0.0f);
            float ov = __fmul_rn(ow, oh);
            float un = fmaxf(__fsub_rn(__fadd_rn(ai, area[j]), ov), 1e-10f);
            float iou = __fdiv_rn(ov, un);
            if (iou > 0.6f) bits |= (1ull << e);
        }
        sup[i][w] = bits;
    }
    __syncthreads();

    // greedy suppression: 3 lanes hold keep-words, one-ahead prefetch
    if (tid < 64) {
        const int l = tid;
        u64 kw   = (l < 3) ? keepw[l]  : 0ull;
        u64 scur = (l < 3) ? sup[0][l] : 0ull;
        for (int i = 0; i < MAXN; ++i) {
            u64 snext = (l < 3 && i + 1 < MAXN) ? sup[i + 1][l] : 0ull;
            u64 kwwi = __shfl(kw, i >> 6);
            if ((kwwi >> (i & 63)) & 1ull) {
                int lo = l * 64;
                u64 allow;
                if (i < lo)            allow = ~0ull;
                else if (i - lo >= 63) allow = 0ull;
                else                   allow = ~((1ull << (i - lo + 1)) - 1ull);
                kw &= ~(scur & allow);
            }
            scur = snext;
        }
        if (l < 3) keepw[l] = kw;
    }
    __syncthreads();

    if (tid < MAXN) {
        bool kp = (keepw[tid >> 6] >> (tid & 63)) & 1ull;
        int o = b * MAXN + tid;
        float* oSc = out;
        float* oId = out + NB * MAXN;
        float* oBx = out + 2 * NB * MAXN;
        float* oKp = out + 2 * NB * MAXN + NB * MAXN * 4;
        oSc[o] = kp ? sc[tid] : 0.0f;
        oId[o] = kp ? (float)idv[tid] : 0.0f;
        oBx[o * 4 + 0] = kp ? bx0[tid] : 0.0f;
        oBx[o * 4 + 1] = kp ? bx1[tid] : 0.0f;
        oBx[o * 4 + 2] = kp ? bx2[tid] : 0.0f;
        oBx[o * 4 + 3] = kp ? bx3[tid] : 0.0f;
        oKp[o] = kp ? 1.0f : 0.0f;
    }
}

// ---------------------------------------------------------------------------
extern "C" void kernel_launch(void* const* d_in, const int* in_sizes, int n_in,
                              void* d_out, int out_size, void* d_ws, size_t ws_size,
                              hipStream_t stream)
{
    const float* cls[5]; const float* reg[5]; const float* ctr[5];
    for (int li = 0; li < 5; ++li) {
        cls[li] = (const float*)d_in[3 * li + 0];
        reg[li] = (const float*)d_in[3 * li + 1];
        ctr[li] = (const float*)d_in[3 * li + 2];
    }

    const size_t CAND_BYTES = (size_t)NB * NCHUNK * CAP * sizeof(u64); // ~1.05 MB
    u64* cand = (u64*)d_ws;
    u32* done = (u32*)((char*)d_ws + CAND_BYTES);

    k_zero<<<1, NB, 0, stream>>>(done);

    dim3 g(NCHUNK, NB);
    k_fused<<<g, 256, 0, stream>>>(cls[0], cls[1], cls[2], cls[3], cls[4],
                                   reg[0], reg[1], reg[2], reg[3], reg[4],
                                   ctr[0], ctr[1], ctr[2], ctr[3], ctr[4],
                                   cand, done, (float*)d_out);
}

// Round 8
// 246.655 us; speedup vs baseline: 1.3878x; 1.3878x over previous
//
#include <hip/hip_runtime.h>
#include <cstdint>
#include <cstddef>

#define NPTS 21824
#define NB   64
#define NCLS 20
#define MAXN 150
#define NCHUNK 11
#define CHSZ 2048
#define CAP  186          // candidate cap: 150 <= count <= 186 after select

typedef unsigned long long u64;
typedef unsigned int u32;

// Levels: L0 [0,16384) d=128 s=8 | L1 [16384,20480) d=64 s=16
//         L2 [20480,21504) d=32 s=32 | L3 [21504,21760) d=16 s=64
//         L4 [21760,21824) d=8 s=128   (all bases 8-aligned)

// ---------------------------------------------------------------------------
// Greedy-bit threshold bisection (round-6 proven): largest T with
// count(key>=T) >= MAXN, early-stop once count <= CAP. 256 threads, 8 keys
// per thread in registers. Keys distinct (unique point idx in low bits).
// ---------------------------------------------------------------------------
__device__ __forceinline__ u64 bisect_threshold(const u64 (&key)[8], int total,
                                                int (*wcnt)[4], int cap)
{
    const int tid  = threadIdx.x;
    const int lane = tid & 63, wv = tid >> 6;
    u64 T = 0;
    int count = total;
    int it = 0;
    for (int bbit = 62; bbit >= 0; --bbit) {
        if (bbit == 31) bbit = 14;       // skip structurally-zero bits
        if (count <= cap) break;
        u64 Tt = T | (1ull << bbit);
        int c = 0;
        #pragma unroll
        for (int i = 0; i < 8; ++i) c += (key[i] >= Tt) ? 1 : 0;
        for (int off = 32; off; off >>= 1) c += __shfl_xor(c, off);
        if (lane == 0) wcnt[it & 1][wv] = c;
        __syncthreads();
        int tot = wcnt[it & 1][0] + wcnt[it & 1][1]
                + wcnt[it & 1][2] + wcnt[it & 1][3];
        if (tot >= MAXN) { T = Tt; count = tot; }
        ++it;
    }
    return T;
}

// ---------------------------------------------------------------------------
// K1 (byte-identical to round 6): fused scores + per-(batch,chunk) pruning.
// ---------------------------------------------------------------------------
__global__ __launch_bounds__(256) void k_part(
    const float* __restrict__ c0, const float* __restrict__ c1,
    const float* __restrict__ c2, const float* __restrict__ c3,
    const float* __restrict__ c4,
    const float* __restrict__ t0, const float* __restrict__ t1,
    const float* __restrict__ t2, const float* __restrict__ t3,
    const float* __restrict__ t4,
    u64* __restrict__ cand)
{
    __shared__ int wcnt[2][4];
    __shared__ int cnt;
    const int tid   = threadIdx.x;
    const int chunk = blockIdx.x;
    const int b     = blockIdx.y;
    const int pl    = tid * 8;
    const int p0    = chunk * CHSZ + pl;

    u64 key[8];
    #pragma unroll
    for (int i = 0; i < 8; ++i) key[i] = 0;

    if (p0 < NPTS) {
        const float* cp; const float* tp; int base; size_t hw;
        if (p0 < 16384)      { cp = c0; tp = t0; base = 0;     hw = 16384; }
        else if (p0 < 20480) { cp = c1; tp = t1; base = 16384; hw = 4096;  }
        else if (p0 < 21504) { cp = c2; tp = t2; base = 20480; hw = 1024;  }
        else if (p0 < 21760) { cp = c3; tp = t3; base = 21504; hw = 256;   }
        else                 { cp = c4; tp = t4; base = 21760; hw = 64;    }
        int q = p0 - base;
        const float* cb = cp + (size_t)b * NCLS * hw + q;

        float4 m0 = *reinterpret_cast<const float4*>(cb);
        float4 m1 = *reinterpret_cast<const float4*>(cb + 4);
        for (int c = 1; c < NCLS; ++c) {
            float4 v0 = *reinterpret_cast<const float4*>(cb + (size_t)c * hw);
            float4 v1 = *reinterpret_cast<const float4*>(cb + (size_t)c * hw + 4);
            m0.x = fmaxf(m0.x, v0.x); m0.y = fmaxf(m0.y, v0.y);
            m0.z = fmaxf(m0.z, v0.z); m0.w = fmaxf(m0.w, v0.w);
            m1.x = fmaxf(m1.x, v1.x); m1.y = fmaxf(m1.y, v1.y);
            m1.z = fmaxf(m1.z, v1.z); m1.w = fmaxf(m1.w, v1.w);
        }
        const float* tb = tp + (size_t)b * hw + q;
        float4 q0 = *reinterpret_cast<const float4*>(tb);
        float4 q1 = *reinterpret_cast<const float4*>(tb + 4);

        float mm[8] = {m0.x, m0.y, m0.z, m0.w, m1.x, m1.y, m1.z, m1.w};
        float cc[8] = {q0.x, q0.y, q0.z, q0.w, q1.x, q1.y, q1.z, q1.w};
        #pragma unroll
        for (int i = 0; i < 8; ++i) {
            // bit-exact to max-of-sigmoids: expf monotone, 1/(1+u) antitone
            float best = 1.0f / (1.0f + expf(-mm[i]));
            float sct  = 1.0f / (1.0f + expf(-cc[i]));
            float sc   = sqrtf(__fmul_rn(best, sct));
            key[i] = ((u64)__float_as_uint(sc) << 32)
                   | (u32)(21823 - (p0 + i));
        }
    }

    u64 T = bisect_threshold(key, CHSZ, wcnt, CAP);

    if (tid == 0) cnt = 0;
    __syncthreads();
    u64* outp = cand + ((size_t)b * NCHUNK + chunk) * CAP;
    #pragma unroll
    for (int i = 0; i < 8; ++i) {
        if (key[i] >= T) {
            int pos = atomicAdd(&cnt, 1);
            if (pos < CAP) outp[pos] = key[i];
        }
    }
    __syncthreads();
    for (int i = cnt + tid; i < CAP; i += 256) outp[i] = 0;  // pad
}

// ---------------------------------------------------------------------------
// K2: per-batch merge 11x186 -> exact sorted top-150 keys -> global srt_g.
// ---------------------------------------------------------------------------
__global__ __launch_bounds__(256) void k_sel(
    const u64* __restrict__ cand, u64* __restrict__ srt_g)
{
    const int NC2 = NCHUNK * CAP;   // 2046
    __shared__ int wcnt[2][4];
    __shared__ int cnt;
    __shared__ u64 win[CAP];

    const int b = blockIdx.x, tid = threadIdx.x;

    u64 key[8];
    #pragma unroll
    for (int j = 0; j < 8; ++j) {
        int i = j * 256 + tid;
        key[j] = (i < NC2) ? cand[(size_t)b * NC2 + i] : 0ull;
    }

    u64 T = bisect_threshold(key, CHSZ, wcnt, CAP);

    if (tid == 0) cnt = 0;
    __syncthreads();
    #pragma unroll
    for (int j = 0; j < 8; ++j) {
        if (key[j] >= T) {
            int pos = atomicAdd(&cnt, 1);
            if (pos < CAP) win[pos] = key[j];
        }
    }
    __syncthreads();
    int C = min(cnt, CAP);          // >= MAXN guaranteed (threshold contract)
    if (tid < C) {                  // rank-sort: distinct keys -> permutation
        u64 mk = win[tid]; int r = 0;
        for (int j = 0; j < C; ++j) r += (win[j] > mk) ? 1 : 0;
        if (r < MAXN) srt_g[(size_t)b * MAXN + r] = mk;
    }
}

// ---------------------------------------------------------------------------
// K3: per-batch id-recompute (600 parallel 5-class tasks, exact first-max
// combine), box decode (parallel), reference-exact class-offset NMS, outputs.
// ---------------------------------------------------------------------------
__global__ __launch_bounds__(1024) void k_out(
    const float* __restrict__ c0, const float* __restrict__ c1,
    const float* __restrict__ c2, const float* __restrict__ c3,
    const float* __restrict__ c4,
    const float* __restrict__ r0, const float* __restrict__ r1,
    const float* __restrict__ r2, const float* __restrict__ r3,
    const float* __restrict__ r4,
    const u64* __restrict__ srt_g,
    float* __restrict__ out)
{
    __shared__ int   parr[MAXN];
    __shared__ u64   pid[MAXN][4];
    __shared__ float bx0[MAXN], bx1[MAXN], bx2[MAXN], bx3[MAXN];
    __shared__ float ox1[MAXN], oy1[MAXN], ox2[MAXN], oy2[MAXN], area[MAXN];
    __shared__ float sc[MAXN];
    __shared__ int   idv[MAXN];
    __shared__ u64 sup[MAXN][3];
    __shared__ u64 keepw[3];
    __shared__ float shcmax;
    __shared__ float wmax[16];

    const int b = blockIdx.x, tid = threadIdx.x;

    if (tid < MAXN) {
        u64 kk = srt_g[(size_t)b * MAXN + tid];
        sc[tid]   = __uint_as_float((u32)(kk >> 32));
        parr[tid] = 21823 - (int)(kk & 0x7FFFu);
    }
    __syncthreads();

    if (tid < MAXN * 4) {
        // id partial: winner w, class group g (classes 5g..5g+4)
        int w = tid >> 2, g = tid & 3;
        int p = parr[w];
        const float* cp; int base; size_t hw;
        if (p < 16384)      { cp = c0; base = 0;     hw = 16384; }
        else if (p < 20480) { cp = c1; base = 16384; hw = 4096;  }
        else if (p < 21504) { cp = c2; base = 20480; hw = 1024;  }
        else if (p < 21760) { cp = c3; base = 21504; hw = 256;   }
        else                { cp = c4; base = 21760; hw = 64;    }
        const float* cb = cp + (size_t)b * NCLS * hw + (p - base);
        float best = -1.0f; int bi = 0;
        #pragma unroll
        for (int j = 0; j < 5; ++j) {
            int c = g * 5 + j;
            float v  = cb[(size_t)c * hw];
            float sg = 1.0f / (1.0f + expf(-v));   // reference sigmoid
            if (sg > best) { best = sg; bi = c; }  // first max wins
        }
        // pack: higher sg wins; tie -> lower class index (31-bi larger)
        pid[w][g] = ((u64)__float_as_uint(best) << 32) | (u32)(31 - bi);
    } else if (tid < MAXN * 4 + MAXN) {
        // box decode: winner w
        int w = tid - MAXN * 4;
        int p = parr[w];
        const float* rp; int base, dim, lg, st;
        if (p < 16384)      { rp = r0; base = 0;     dim = 128; lg = 7; st = 8;   }
        else if (p < 20480) { rp = r1; base = 16384; dim = 64;  lg = 6; st = 16;  }
        else if (p < 21504) { rp = r2; base = 20480; dim = 32;  lg = 5; st = 32;  }
        else if (p < 21760) { rp = r3; base = 21504; dim = 16;  lg = 4; st = 64;  }
        else                { rp = r4; base = 21760; dim = 8;   lg = 3; st = 128; }
        int q = p - base;
        int y = q >> lg;
        int x = q & (dim - 1);
        float s  = (float)st;
        float cx = (float)(x * st + (st >> 1));
        float cy = (float)(y * st + (st >> 1));
        size_t hw = (size_t)dim * dim;
        const float* rg = rp + (size_t)b * 4 * hw + q;
        float a0 = rg[0], a1 = rg[hw], a2 = rg[2 * hw], a3 = rg[3 * hw];
        bx0[w] = __fsub_rn(cx, __fmul_rn(a0, s));
        bx1[w] = __fsub_rn(cy, __fmul_rn(a1, s));
        bx2[w] = __fadd_rn(cx, __fmul_rn(a2, s));
        bx3[w] = __fadd_rn(cy, __fmul_rn(a3, s));
    }
    __syncthreads();

    if (tid < MAXN) {
        u64 m0 = pid[tid][0], m1 = pid[tid][1];
        u64 m2 = pid[tid][2], m3 = pid[tid][3];
        u64 mbest = m0;
        if (m1 > mbest) mbest = m1;
        if (m2 > mbest) mbest = m2;
        if (m3 > mbest) mbest = m3;
        idv[tid] = (31 - (int)(mbest & 31u)) + 1;
    }
    __syncthreads();

    // coord_max over valid boxes — shuffle reduce, 16 wave maxes
    float m = -INFINITY;
    if (tid < MAXN && sc[tid] > 0.05f)
        m = fmaxf(fmaxf(bx0[tid], bx1[tid]), fmaxf(bx2[tid], bx3[tid]));
    #pragma unroll
    for (int off = 32; off >= 1; off >>= 1) m = fmaxf(m, __shfl_xor(m, off));
    if ((tid & 63) == 0) wmax[tid >> 6] = m;
    if (tid < 192) {                 // valid mask via ballot (waves 0..2)
        bool val = (tid < MAXN) && (sc[tid] > 0.05f);
        u64 mask = __ballot(val);
        if ((tid & 63) == 0) keepw[tid >> 6] = mask;
    }
    __syncthreads();
    if (tid == 0) {
        float mm = -INFINITY;
        #pragma unroll
        for (int w = 0; w < 16; ++w) mm = fmaxf(mm, wmax[w]);
        shcmax = isfinite(mm) ? mm : 0.0f;
    }
    __syncthreads();

    float cm1 = __fadd_rn(shcmax, 1.0f);
    if (tid < MAXN) {
        float off = __fmul_rn((float)idv[tid], cm1);
        float X1 = __fadd_rn(bx0[tid], off);
        float Y1 = __fadd_rn(bx1[tid], off);
        float X2 = __fadd_rn(bx2[tid], off);
        float Y2 = __fadd_rn(bx3[tid], off);
        ox1[tid] = X1; oy1[tid] = Y1; ox2[tid] = X2; oy2[tid] = Y2;
        area[tid] = __fmul_rn(__fadd_rn(__fsub_rn(X2, X1), 1.0f),
                              __fadd_rn(__fsub_rn(Y2, Y1), 1.0f));
    }
    __syncthreads();

    // suppression bitmask rows: 450 tasks, one pass
    if (tid < MAXN * 3) {
        int i = tid / 3;
        int w = tid - i * 3;
        float x1i = ox1[i], y1i = oy1[i], x2i = ox2[i], y2i = oy2[i], ai = area[i];
        u64 bits = 0ull;
        for (int e = 0; e < 64; ++e) {
            int j = w * 64 + e;
            if (j >= MAXN) break;
            float xmin = fmaxf(x1i, ox1[j]);
            float ymin = fmaxf(y1i, oy1[j]);
            float xmax = fminf(x2i, ox2[j]);
            float ymax = fminf(y2i, oy2[j]);
            float ow = fmaxf(__fsub_rn(xmax, xmin), 0.0f);
            float oh = fmaxf(__fsub_rn(ymax, ymin), 0.0f);
            float ov = __fmul_rn(ow, oh);
            float un = fmaxf(__fsub_rn(__fadd_rn(ai, area[j]), ov), 1e-10f);
            float iou = __fdiv_rn(ov, un);
            if (iou > 0.6f) bits |= (1ull << e);
        }
        sup[i][w] = bits;
    }
    __syncthreads();

    // greedy suppression: 3 lanes hold keep-words, one-ahead prefetch
    if (tid < 64) {
        const int l = tid;
        u64 kw   = (l < 3) ? keepw[l]  : 0ull;
        u64 scur = (l < 3) ? sup[0][l] : 0ull;
        for (int i = 0; i < MAXN; ++i) {
            u64 snext = (l < 3 && i + 1 < MAXN) ? sup[i + 1][l] : 0ull;
            u64 kwwi = __shfl(kw, i >> 6);
            if ((kwwi >> (i & 63)) & 1ull) {
                int lo = l * 64;
                u64 allow;
                if (i < lo)            allow = ~0ull;
                else if (i - lo >= 63) allow = 0ull;
                else                   allow = ~((1ull << (i - lo + 1)) - 1ull);
                kw &= ~(scur & allow);
            }
            scur = snext;
        }
        if (l < 3) keepw[l] = kw;
    }
    __syncthreads();

    if (tid < MAXN) {
        bool kp = (keepw[tid >> 6] >> (tid & 63)) & 1ull;
        int o = b * MAXN + tid;
        float* oSc = out;
        float* oId = out + NB * MAXN;
        float* oBx = out + 2 * NB * MAXN;
        float* oKp = out + 2 * NB * MAXN + NB * MAXN * 4;
        oSc[o] = kp ? sc[tid] : 0.0f;
        oId[o] = kp ? (float)idv[tid] : 0.0f;
        oBx[o * 4 + 0] = kp ? bx0[tid] : 0.0f;
        oBx[o * 4 + 1] = kp ? bx1[tid] : 0.0f;
        oBx[o * 4 + 2] = kp ? bx2[tid] : 0.0f;
        oBx[o * 4 + 3] = kp ? bx3[tid] : 0.0f;
        oKp[o] = kp ? 1.0f : 0.0f;
    }
}

// ---------------------------------------------------------------------------
extern "C" void kernel_launch(void* const* d_in, const int* in_sizes, int n_in,
                              void* d_out, int out_size, void* d_ws, size_t ws_size,
                              hipStream_t stream)
{
    const float* cls[5]; const float* reg[5]; const float* ctr[5];
    for (int li = 0; li < 5; ++li) {
        cls[li] = (const float*)d_in[3 * li + 0];
        reg[li] = (const float*)d_in[3 * li + 1];
        ctr[li] = (const float*)d_in[3 * li + 2];
    }

    const size_t CAND_BYTES = (size_t)NB * NCHUNK * CAP * sizeof(u64);
    u64* cand  = (u64*)d_ws;
    u64* srt_g = (u64*)((char*)d_ws + CAND_BYTES);

    dim3 g1(NCHUNK, NB);
    k_part<<<g1, 256, 0, stream>>>(cls[0], cls[1], cls[2], cls[3], cls[4],
                                   ctr[0], ctr[1], ctr[2], ctr[3], ctr[4],
                                   cand);
    k_sel<<<NB, 256, 0, stream>>>(cand, srt_g);
    k_out<<<NB, 1024, 0, stream>>>(cls[0], cls[1], cls[2], cls[3], cls[4],
                                   reg[0], reg[1], reg[2], reg[3], reg[4],
                                   srt_g, (float*)d_out);
}

// Round 9
// 238.136 us; speedup vs baseline: 1.4375x; 1.0358x over previous
//
#include <hip/hip_runtime.h>
#include <cstdint>
#include <cstddef>

#define NPTS 21824
#define NB   64
#define NCLS 20
#define MAXN 150
#define NCHUNK 11
#define CHSZ 2048
#define CAP  186          // candidate cap: 150 <= count <= 186 after select

typedef unsigned long long u64;
typedef unsigned int u32;

// Levels: L0 [0,16384) d=128 s=8 | L1 [16384,20480) d=64 s=16
//         L2 [20480,21504) d=32 s=32 | L3 [21504,21760) d=16 s=64
//         L4 [21760,21824) d=8 s=128   (all bases/sizes multiples of 4)

// ---------------------------------------------------------------------------
// Greedy-bit threshold bisection (proven r6/r8): largest T with
// count(key>=T) >= MAXN, early-stop once count <= cap. Keys in registers,
// distinct (unique point idx in low bits). Uniform control flow.
// ---------------------------------------------------------------------------
template<int TPB, int K>
__device__ __forceinline__ u64 bisect_threshold(const u64 (&key)[K],
                                                int (*wcnt)[TPB / 64],
                                                int total, int cap)
{
    const int tid  = threadIdx.x;
    const int lane = tid & 63, wv = tid >> 6;
    constexpr int NW = TPB / 64;
    u64 T = 0;
    int count = total;
    int it = 0;
    for (int bbit = 62; bbit >= 0; --bbit) {
        if (bbit == 31) bbit = 14;       // skip structurally-zero bits
        if (count <= cap) break;
        u64 Tt = T | (1ull << bbit);
        int c = 0;
        #pragma unroll
        for (int i = 0; i < K; ++i) c += (key[i] >= Tt) ? 1 : 0;
        #pragma unroll
        for (int off = 32; off; off >>= 1) c += __shfl_xor(c, off);
        if (lane == 0) wcnt[it & 1][wv] = c;
        __syncthreads();
        int tot = 0;
        #pragma unroll
        for (int w = 0; w < NW; ++w) tot += wcnt[it & 1][w];
        if (tot >= MAXN) { T = Tt; count = tot; }
        ++it;
    }
    return T;
}

// ---------------------------------------------------------------------------
// K1: fused scores + per-(batch,chunk) pruning. 512 thr x 4 pts, class loop
// fully unrolled for MLP. score math bit-identical to passing kernel.
// ---------------------------------------------------------------------------
__global__ __launch_bounds__(512, 4) void k_part(
    const float* __restrict__ c0, const float* __restrict__ c1,
    const float* __restrict__ c2, const float* __restrict__ c3,
    const float* __restrict__ c4,
    const float* __restrict__ t0, const float* __restrict__ t1,
    const float* __restrict__ t2, const float* __restrict__ t3,
    const float* __restrict__ t4,
    u64* __restrict__ cand)
{
    __shared__ int wcnt[2][8];
    __shared__ int cnt;
    const int tid   = threadIdx.x;
    const int chunk = blockIdx.x;
    const int b     = blockIdx.y;
    const int p0    = chunk * CHSZ + tid * 4;

    u64 key[4] = {0ull, 0ull, 0ull, 0ull};

    if (p0 < NPTS) {
        const float* cp; const float* tp; int base; size_t hw;
        if (p0 < 16384)      { cp = c0; tp = t0; base = 0;     hw = 16384; }
        else if (p0 < 20480) { cp = c1; tp = t1; base = 16384; hw = 4096;  }
        else if (p0 < 21504) { cp = c2; tp = t2; base = 20480; hw = 1024;  }
        else if (p0 < 21760) { cp = c3; tp = t3; base = 21504; hw = 256;   }
        else                 { cp = c4; tp = t4; base = 21760; hw = 64;    }
        int q = p0 - base;               // 4-aligned
        const float* cb = cp + (size_t)b * NCLS * hw + q;

        float4 mx = *reinterpret_cast<const float4*>(cb);
        #pragma unroll
        for (int c = 1; c < NCLS; ++c) { // 19 independent loads, fmax chain
            float4 v = *reinterpret_cast<const float4*>(cb + (size_t)c * hw);
            mx.x = fmaxf(mx.x, v.x); mx.y = fmaxf(mx.y, v.y);
            mx.z = fmaxf(mx.z, v.z); mx.w = fmaxf(mx.w, v.w);
        }
        float4 cv = *reinterpret_cast<const float4*>(tp + (size_t)b * hw + q);

        float mm[4] = {mx.x, mx.y, mx.z, mx.w};
        float cc[4] = {cv.x, cv.y, cv.z, cv.w};
        #pragma unroll
        for (int i = 0; i < 4; ++i) {
            // bit-exact to max-of-sigmoids: expf monotone, 1/(1+u) antitone
            float best = 1.0f / (1.0f + expf(-mm[i]));
            float sct  = 1.0f / (1.0f + expf(-cc[i]));
            float s    = sqrtf(__fmul_rn(best, sct));
            key[i] = ((u64)__float_as_uint(s) << 32)
                   | (u32)(21823 - (p0 + i));
        }
    }

    u64 T = bisect_threshold<512, 4>(key, wcnt, CHSZ, CAP);

    if (tid == 0) cnt = 0;
    __syncthreads();
    u64* outp = cand + ((size_t)b * NCHUNK + chunk) * CAP;
    #pragma unroll
    for (int i = 0; i < 4; ++i) {
        if (key[i] >= T) {
            int pos = atomicAdd(&cnt, 1);
            if (pos < CAP) outp[pos] = key[i];
        }
    }
    __syncthreads();
    for (int i = cnt + tid; i < CAP; i += 512) outp[i] = 0;  // pad
}

// ---------------------------------------------------------------------------
// K2: per-batch merge 11x186 -> exact sorted top-150 (bisect + rank-sort),
// parallel id-recompute + decode (750 tasks), reference-exact NMS, outputs.
// ---------------------------------------------------------------------------
__global__ __launch_bounds__(512) void k_out(
    const float* __restrict__ c0, const float* __restrict__ c1,
    const float* __restrict__ c2, const float* __restrict__ c3,
    const float* __restrict__ c4,
    const float* __restrict__ r0, const float* __restrict__ r1,
    const float* __restrict__ r2, const float* __restrict__ r3,
    const float* __restrict__ r4,
    const u64* __restrict__ cand,
    float* __restrict__ out)
{
    const int NC2 = NCHUNK * CAP;   // 2046
    __shared__ int wcnt[2][8];
    __shared__ int cnt;
    __shared__ u64 win[CAP];
    __shared__ u64 srt[MAXN];
    __shared__ int   parr[MAXN];
    __shared__ u64   pid[MAXN][4];
    __shared__ float bx0[MAXN], bx1[MAXN], bx2[MAXN], bx3[MAXN];
    __shared__ float ox1[MAXN], oy1[MAXN], ox2[MAXN], oy2[MAXN], area[MAXN];
    __shared__ float sc[MAXN];
    __shared__ int   idv[MAXN];
    __shared__ u64 sup[MAXN][3];
    __shared__ u64 keepw[3];
    __shared__ float shcmax;
    __shared__ float wmax[8];

    const int b = blockIdx.x, tid = threadIdx.x;

    // ---- merge-select: exact global top-150 of 11x186 candidates ----------
    u64 key[4];
    #pragma unroll
    for (int j = 0; j < 4; ++j) {
        int i = j * 512 + tid;
        key[j] = (i < NC2) ? cand[(size_t)b * NC2 + i] : 0ull;
    }

    u64 T = bisect_threshold<512, 4>(key, wcnt, 2048, CAP);

    if (tid == 0) cnt = 0;
    if (tid < MAXN) srt[tid] = 0ull;
    __syncthreads();
    #pragma unroll
    for (int j = 0; j < 4; ++j) {
        if (key[j] >= T) {
            int pos = atomicAdd(&cnt, 1);
            if (pos < CAP) win[pos] = key[j];
        }
    }
    __syncthreads();
    int C = min(cnt, CAP);          // >= MAXN by threshold contract
    if (tid < C) {                  // rank-sort: distinct keys -> permutation
        u64 mk = win[tid]; int r = 0;
        for (int j = 0; j < C; ++j) r += (win[j] > mk) ? 1 : 0;
        if (r < MAXN) srt[r] = mk;
    }
    __syncthreads();

    if (tid < MAXN) {
        u64 kk = srt[tid];
        sc[tid]   = __uint_as_float((u32)(kk >> 32));
        parr[tid] = 21823 - (int)(kk & 0x7FFFu);
    }
    __syncthreads();

    // ---- 750 scattered tasks: 600 id-partials + 150 decodes ---------------
    for (int t = tid; t < MAXN * 5; t += 512) {
        if (t < MAXN * 4) {
            int w = t >> 2, g = t & 3;    // winner w, classes 5g..5g+4
            int p = parr[w];
            const float* cp; int base; size_t hw;
            if (p < 16384)      { cp = c0; base = 0;     hw = 16384; }
            else if (p < 20480) { cp = c1; base = 16384; hw = 4096;  }
            else if (p < 21504) { cp = c2; base = 20480; hw = 1024;  }
            else if (p < 21760) { cp = c3; base = 21504; hw = 256;   }
            else                { cp = c4; base = 21760; hw = 64;    }
            const float* cb = cp + (size_t)b * NCLS * hw + (p - base);
            float best = -1.0f; int bi = 0;
            #pragma unroll
            for (int j = 0; j < 5; ++j) {
                int c = g * 5 + j;
                float v  = cb[(size_t)c * hw];
                float sg = 1.0f / (1.0f + expf(-v));   // reference sigmoid
                if (sg > best) { best = sg; bi = c; }  // first max wins
            }
            // pack: higher sg wins; tie -> lower class index (31-bi larger)
            pid[w][g] = ((u64)__float_as_uint(best) << 32) | (u32)(31 - bi);
        } else {
            int w = t - MAXN * 4;         // decode winner w
            int p = parr[w];
            const float* rp; int base, dim, lg, st;
            if (p < 16384)      { rp = r0; base = 0;     dim = 128; lg = 7; st = 8;   }
            else if (p < 20480) { rp = r1; base = 16384; dim = 64;  lg = 6; st = 16;  }
            else if (p < 21504) { rp = r2; base = 20480; dim = 32;  lg = 5; st = 32;  }
            else if (p < 21760) { rp = r3; base = 21504; dim = 16;  lg = 4; st = 64;  }
            else                { rp = r4; base = 21760; dim = 8;   lg = 3; st = 128; }
            int q = p - base;
            int y = q >> lg;
            int x = q & (dim - 1);
            float s  = (float)st;
            float cx = (float)(x * st + (st >> 1));
            float cy = (float)(y * st + (st >> 1));
            size_t hw = (size_t)dim * dim;
            const float* rg = rp + (size_t)b * 4 * hw + q;
            float a0 = rg[0], a1 = rg[hw], a2 = rg[2 * hw], a3 = rg[3 * hw];
            bx0[w] = __fsub_rn(cx, __fmul_rn(a0, s));
            bx1[w] = __fsub_rn(cy, __fmul_rn(a1, s));
            bx2[w] = __fadd_rn(cx, __fmul_rn(a2, s));
            bx3[w] = __fadd_rn(cy, __fmul_rn(a3, s));
        }
    }
    __syncthreads();

    if (tid < MAXN) {                    // exact first-max-wins combine
        u64 m0 = pid[tid][0], m1 = pid[tid][1];
        u64 m2 = pid[tid][2], m3 = pid[tid][3];
        u64 mbest = m0;
        if (m1 > mbest) mbest = m1;
        if (m2 > mbest) mbest = m2;
        if (m3 > mbest) mbest = m3;
        idv[tid] = (31 - (int)(mbest & 31u)) + 1;
    }
    __syncthreads();

    // coord_max over valid boxes — shuffle reduce, 8 wave maxes
    float m = -INFINITY;
    if (tid < MAXN && sc[tid] > 0.05f)
        m = fmaxf(fmaxf(bx0[tid], bx1[tid]), fmaxf(bx2[tid], bx3[tid]));
    #pragma unroll
    for (int off = 32; off >= 1; off >>= 1) m = fmaxf(m, __shfl_xor(m, off));
    if ((tid & 63) == 0) wmax[tid >> 6] = m;
    if (tid < 192) {                 // valid mask via ballot (waves 0..2)
        bool val = (tid < MAXN) && (sc[tid] > 0.05f);
        u64 mask = __ballot(val);
        if ((tid & 63) == 0) keepw[tid >> 6] = mask;
    }
    __syncthreads();
    if (tid == 0) {
        float mm = -INFINITY;
        #pragma unroll
        for (int w = 0; w < 8; ++w) mm = fmaxf(mm, wmax[w]);
        shcmax = isfinite(mm) ? mm : 0.0f;
    }
    __syncthreads();

    float cm1 = __fadd_rn(shcmax, 1.0f);
    if (tid < MAXN) {
        float off = __fmul_rn((float)idv[tid], cm1);
        float X1 = __fadd_rn(bx0[tid], off);
        float Y1 = __fadd_rn(bx1[tid], off);
        float X2 = __fadd_rn(bx2[tid], off);
        float Y2 = __fadd_rn(bx3[tid], off);
        ox1[tid] = X1; oy1[tid] = Y1; ox2[tid] = X2; oy2[tid] = Y2;
        area[tid] = __fmul_rn(__fadd_rn(__fsub_rn(X2, X1), 1.0f),
                              __fadd_rn(__fsub_rn(Y2, Y1), 1.0f));
    }
    __syncthreads();

    // suppression bitmask rows: 450 tasks, one pass
    if (tid < MAXN * 3) {
        int i = tid / 3;
        int w = tid - i * 3;
        float x1i = ox1[i], y1i = oy1[i], x2i = ox2[i], y2i = oy2[i], ai = area[i];
        u64 bits = 0ull;
        for (int e = 0; e < 64; ++e) {
            int j = w * 64 + e;
            if (j >= MAXN) break;
            float xmin = fmaxf(x1i, ox1[j]);
            float ymin = fmaxf(y1i, oy1[j]);
            float xmax = fminf(x2i, ox2[j]);
            float ymax = fminf(y2i, oy2[j]);
            float ow = fmaxf(__fsub_rn(xmax, xmin), 0.0f);
            float oh = fmaxf(__fsub_rn(ymax, ymin), 0.0f);
            float ov = __fmul_rn(ow, oh);
            float un = fmaxf(__fsub_rn(__fadd_rn(ai, area[j]), ov), 1e-10f);
            float iou = __fdiv_rn(ov, un);
            if (iou > 0.6f) bits |= (1ull << e);
        }
        sup[i][w] = bits;
    }
    __syncthreads();

    // greedy suppression: 3 lanes hold keep-words, one-ahead prefetch
    if (tid < 64) {
        const int l = tid;
        u64 kw   = (l < 3) ? keepw[l]  : 0ull;
        u64 scur = (l < 3) ? sup[0][l] : 0ull;
        for (int i = 0; i < MAXN; ++i) {
            u64 snext = (l < 3 && i + 1 < MAXN) ? sup[i + 1][l] : 0ull;
            u64 kwwi = __shfl(kw, i >> 6);
            if ((kwwi >> (i & 63)) & 1ull) {
                int lo = l * 64;
                u64 allow;
                if (i < lo)            allow = ~0ull;
                else if (i - lo >= 63) allow = 0ull;
                else                   allow = ~((1ull << (i - lo + 1)) - 1ull);
                kw &= ~(scur & allow);
            }
            scur = snext;
        }
        if (l < 3) keepw[l] = kw;
    }
    __syncthreads();

    if (tid < MAXN) {
        bool kp = (keepw[tid >> 6] >> (tid & 63)) & 1ull;
        int o = b * MAXN + tid;
        float* oSc = out;
        float* oId = out + NB * MAXN;
        float* oBx = out + 2 * NB * MAXN;
        float* oKp = out + 2 * NB * MAXN + NB * MAXN * 4;
        oSc[o] = kp ? sc[tid] : 0.0f;
        oId[o] = kp ? (float)idv[tid] : 0.0f;
        oBx[o * 4 + 0] = kp ? bx0[tid] : 0.0f;
        oBx[o * 4 + 1] = kp ? bx1[tid] : 0.0f;
        oBx[o * 4 + 2] = kp ? bx2[tid] : 0.0f;
        oBx[o * 4 + 3] = kp ? bx3[tid] : 0.0f;
        oKp[o] = kp ? 1.0f : 0.0f;
    }
}

// ---------------------------------------------------------------------------
extern "C" void kernel_launch(void* const* d_in, const int* in_sizes, int n_in,
                              void* d_out, int out_size, void* d_ws, size_t ws_size,
                              hipStream_t stream)
{
    const float* cls[5]; const float* reg[5]; const float* ctr[5];
    for (int li = 0; li < 5; ++li) {
        cls[li] = (const float*)d_in[3 * li + 0];
        reg[li] = (const float*)d_in[3 * li + 1];
        ctr[li] = (const float*)d_in[3 * li + 2];
    }

    u64* cand = (u64*)d_ws;   // NB * NCHUNK * CAP u64 ~= 1.05 MB

    dim3 g1(NCHUNK, NB);
    k_part<<<g1, 512, 0, stream>>>(cls[0], cls[1], cls[2], cls[3], cls[4],
                                   ctr[0], ctr[1], ctr[2], ctr[3], ctr[4],
                                   cand);
    k_out<<<NB, 512, 0, stream>>>(cls[0], cls[1], cls[2], cls[3], cls[4],
                                  reg[0], reg[1], reg[2], reg[3], reg[4],
                                  cand, (float*)d_out);
}